// Round 11
// baseline (433.920 us; speedup 1.0000x reference)
//
#include <hip/hip_runtime.h>
#include <hip/hip_fp16.h>
#include <cstddef>

#define EPS 1e-5f
#define TILE 4096    // edges per bhist block (16 per thread, block=256)
#define PTILE 8192   // edges per partition block (16 per thread, block=512)

typedef float nf4 __attribute__((ext_vector_type(4)));   // native vec for nontemporal builtins

// ---------------- init: zero stats + bucket histogram ----------------
__global__ void k_init(float* __restrict__ stats, int* __restrict__ bhist) {
    int t = threadIdx.x;            // single block of 512
    if (t < 256) stats[t] = 0.f;    // 4 layers x (S1+S2) blocks of 32 floats
    bhist[t] = 0;                   // 512 >= nbk
}

// ---------------- coarse bucket histogram (dst >> 8), LDS-aggregated ----------------
__global__ void k_bhist(const int* __restrict__ dst, int* __restrict__ bhist,
                        int E, int nbk) {
    __shared__ int hist[512];
    int tid = threadIdx.x;
    int tile0 = blockIdx.x * TILE;
    for (int i = tid; i < nbk; i += 256) hist[i] = 0;
    __syncthreads();
    #pragma unroll
    for (int k = 0; k < 16; ++k) {
        int e = tile0 + k * 256 + tid;
        if (e < E) atomicAdd(&hist[dst[e] >> 8], 1);
    }
    __syncthreads();
    for (int i = tid; i < nbk; i += 256) {
        int c = hist[i];
        if (c) atomicAdd(&bhist[i], c);
    }
}

// ---------------- scan bucket counts -> bucket offsets (1 block of 512) ----------------
__global__ void k_bscan(const int* __restrict__ bhist, int* __restrict__ bcur,
                        int* __restrict__ bstart, int nbk, int E) {
    __shared__ int tmp[512];
    int t = threadIdx.x;
    int v = (t < nbk) ? bhist[t] : 0;
    tmp[t] = v;
    __syncthreads();
    for (int off = 1; off < 512; off <<= 1) {
        int y = (t >= off) ? tmp[t - off] : 0;
        __syncthreads();
        tmp[t] += y;
        __syncthreads();
    }
    if (t < nbk) { int ex = tmp[t] - v; bcur[t] = ex; bstart[t] = ex; }
    if (t == 0) bstart[nbk] = E;
}

// ---------------- partition: edges -> buckets, packed (dlocal<<24)|src ----------------
__global__ void k_part(const int* __restrict__ src, const int* __restrict__ dst,
                       int* __restrict__ bcur, unsigned int* __restrict__ part,
                       int E, int nbk) {
    __shared__ int hist[512];
    __shared__ int base[512];
    int tid = threadIdx.x;
    int tile0 = blockIdx.x * PTILE;
    for (int i = tid; i < nbk; i += 512) hist[i] = 0;
    __syncthreads();
    unsigned int rec[16];
    int bk[16];
    #pragma unroll
    for (int k = 0; k < 16; ++k) {
        int e = tile0 + k * 512 + tid;
        bk[k] = -1;
        if (e < E) {
            int d = dst[e], s = src[e];
            bk[k] = d >> 8;
            rec[k] = ((unsigned int)(d & 255) << 24) | (unsigned int)s;
            atomicAdd(&hist[bk[k]], 1);
        }
    }
    __syncthreads();
    for (int i = tid; i < nbk; i += 512) {
        int c = hist[i];
        base[i] = c ? atomicAdd(&bcur[i], c) : 0;
        hist[i] = 0;
    }
    __syncthreads();
    #pragma unroll
    for (int k = 0; k < 16; ++k) {
        if (bk[k] >= 0) {
            int r = atomicAdd(&hist[bk[k]], 1);
            part[base[bk[k]] + r] = rec[k];
        }
    }
}

// ---------------- per-bucket: degrees -> row_start + dinv, then csr fill ----------
__global__ void k_fill2(const unsigned int* __restrict__ part, const int* __restrict__ bstart,
                        float* __restrict__ dinv, int* __restrict__ row_start,
                        int* __restrict__ csr_src, int N) {
    __shared__ int hist[256];
    __shared__ int cur[256];
    __shared__ int wsum[8];
    int b = blockIdx.x, tid = threadIdx.x;
    int nbase = b << 8;
    int span0 = bstart[b], span1 = bstart[b + 1];
    if (tid < 256) hist[tid] = 0;
    __syncthreads();
    for (int i = span0 + tid; i < span1; i += 512)
        atomicAdd(&hist[part[i] >> 24], 1);
    __syncthreads();
    int v = (tid < 256) ? hist[tid] : 0;
    int lane = tid & 63, wid = tid >> 6;
    int x = v;
    #pragma unroll
    for (int off = 1; off < 64; off <<= 1) {
        int y = __shfl_up(x, off);
        if (lane >= off) x += y;
    }
    if (lane == 63) wsum[wid] = x;
    __syncthreads();
    int add = 0;
    for (int w = 0; w < wid && w < 4; ++w) add += wsum[w];
    int incl = x + add;
    int rs = span0 + incl - v;          // global exclusive offset (valid for tid<256)
    int node = nbase + tid;
    if (tid < 256 && node < N) {
        row_start[node] = rs;
        dinv[node] = rsqrtf((float)(v + 1));   // +1 self loop
        if (node == N - 1) row_start[N] = rs + v;
    }
    if (tid < 256) cur[tid] = rs;
    __syncthreads();
    for (int i = span0 + tid; i < span1; i += 512) {
        unsigned int rec = part[i];
        int p = atomicAdd(&cur[rec >> 24], 1);
        csr_src[p] = (int)(rec & 0xFFFFFFu);
    }
}

// ---------------- layer 1 linear: 128 -> 8, LDS-tiled; fp16 out ----------------
#define TN 64
__global__ void k_lin1(const float* __restrict__ x, const float* __restrict__ W,
                       const float* __restrict__ dinv,
                       __half* __restrict__ hs, int n) {
    __shared__ float xs[TN * 132];
    __shared__ float ws[128 * 8];
    int tid = threadIdx.x;
    int base = blockIdx.x * TN;
    for (int i = tid; i < 1024; i += 256) ws[i] = W[i];
    int nvalid = n - base; if (nvalid > TN) nvalid = TN;
    int limit4 = nvalid * 32;
    const float4* x4 = (const float4*)(x + (size_t)base * 128);
    float4* xs4 = (float4*)xs;
    for (int i = tid; i < TN * 32; i += 256) {
        if (i < limit4) {
            int row = i >> 5, col = i & 31;
            xs4[row * 33 + col] = x4[i];
        }
    }
    __syncthreads();
    #pragma unroll
    for (int rep = 0; rep < 2; ++rep) {
        int o = rep * 256 + tid;
        int node = o >> 3, feat = o & 7;
        if (node < nvalid) {
            const float* xr = xs + node * 132;
            float s = 0.f;
            #pragma unroll 8
            for (int k = 0; k < 128; ++k) s = fmaf(xr[k], ws[k * 8 + feat], s);
            s *= dinv[base + node];
            hs[(size_t)(base + node) * 8 + feat] = __float2half(s);
        }
    }
}

// ---------------- CSR gather (fp16 rows, fp32 accum) + fused BN-stats ------------
// F/2 threads per node: P = F/8 feature-parts x 4 edge-quarters (subs).
// 8 independent row loads in flight per thread; csr_src cached (L1 sequential).
template<int F>
__global__ void k_gather(const int* __restrict__ row_start, const int* __restrict__ csr_src,
                         const float4* __restrict__ hp, const float* __restrict__ dinv,
                         float* __restrict__ acc, float* __restrict__ S, int n) {
    constexpr int P = F / 8;                 // 16B feature chunks per row
    constexpr int LOGP = (P == 2) ? 1 : 0;
    __shared__ float ls[2 * F];
    if (threadIdx.x < 2 * F) ls[threadIdx.x] = 0.f;
    __syncthreads();

    int t = blockIdx.x * blockDim.x + threadIdx.x;
    int node = t >> (LOGP + 2);
    int part = t & (P - 1);
    int sub  = (t >> LOGP) & 3;              // edge-quarter

    float af[8];
    #pragma unroll
    for (int j = 0; j < 8; ++j) af[j] = 0.f;
    float di = 0.f;

    if (node < n) {
        if (sub == 0) {                      // self-loop term once
            float4 r = hp[(size_t)node * P + part];
            const __half2* h = (const __half2*)&r;
            #pragma unroll
            for (int q = 0; q < 4; ++q) {
                float2 f = __half22float2(h[q]);
                af[2*q] += f.x; af[2*q+1] += f.y;
            }
        }
        int e = row_start[node] + sub, end = row_start[node + 1];
        // 8-wide batch: 8 independent row loads in flight (stride 4 between subs)
        for (; e + 28 < end; e += 32) {
            int sx[8];
            float4 rr[8];
            #pragma unroll
            for (int u = 0; u < 8; ++u) sx[u] = csr_src[e + 4 * u];
            #pragma unroll
            for (int u = 0; u < 8; ++u) rr[u] = hp[(size_t)sx[u] * P + part];
            #pragma unroll
            for (int u = 0; u < 8; ++u) {
                const __half2* h = (const __half2*)&rr[u];
                #pragma unroll
                for (int q = 0; q < 4; ++q) {
                    float2 f = __half22float2(h[q]);
                    af[2*q] += f.x; af[2*q+1] += f.y;
                }
            }
        }
        for (; e + 4 < end; e += 8) {
            int s0 = csr_src[e];
            int s1 = csr_src[e + 4];
            float4 r0 = hp[(size_t)s0 * P + part];
            float4 r1 = hp[(size_t)s1 * P + part];
            const __half2* h0 = (const __half2*)&r0;
            const __half2* h1 = (const __half2*)&r1;
            #pragma unroll
            for (int q = 0; q < 4; ++q) {
                float2 f0 = __half22float2(h0[q]);
                float2 f1 = __half22float2(h1[q]);
                af[2*q]   += f0.x + f1.x;
                af[2*q+1] += f0.y + f1.y;
            }
        }
        if (e < end) {
            int s0 = csr_src[e];
            float4 r0 = hp[(size_t)s0 * P + part];
            const __half2* h0 = (const __half2*)&r0;
            #pragma unroll
            for (int q = 0; q < 4; ++q) {
                float2 f0 = __half22float2(h0[q]);
                af[2*q] += f0.x; af[2*q+1] += f0.y;
            }
        }
        // combine the four edge-quarters (xor P, then xor 2P)
        #pragma unroll
        for (int j = 0; j < 8; ++j) af[j] += __shfl_xor(af[j], P);
        #pragma unroll
        for (int j = 0; j < 8; ++j) af[j] += __shfl_xor(af[j], 2 * P);
        if (sub == 0) {
            nf4* ap = (nf4*)(acc + (size_t)node * F + part * 8);
            nf4 o0, o1;
            o0.x = af[0]; o0.y = af[1]; o0.z = af[2]; o0.w = af[3];
            o1.x = af[4]; o1.y = af[5]; o1.z = af[6]; o1.w = af[7];
            __builtin_nontemporal_store(o0, ap);
            __builtin_nontemporal_store(o1, ap + 1);
            di = dinv[node];                 // stays 0 for sub!=0 -> stats not double-counted
        }
    }

    float s1v[8], s2v[8];
    #pragma unroll
    for (int j = 0; j < 8; ++j) {
        float v = af[j] * di;
        s1v[j] = v; s2v[j] = v * v;
    }
    #pragma unroll
    for (int j = 0; j < 8; ++j) {
        #pragma unroll
        for (int off = 4 * P; off < 64; off <<= 1) {
            s1v[j] += __shfl_down(s1v[j], off);
            s2v[j] += __shfl_down(s2v[j], off);
        }
    }
    int lane = threadIdx.x & 63;
    if (lane < P) {                          // lanes 0..P-1 are sub==0 feature-parts
        int j0 = part * 8;
        #pragma unroll
        for (int j = 0; j < 8; ++j) {
            atomicAdd(&ls[j0 + j], s1v[j]);
            atomicAdd(&ls[F + j0 + j], s2v[j]);
        }
    }
    __syncthreads();
    if (threadIdx.x < 2 * F) atomicAdd(&S[threadIdx.x], ls[threadIdx.x]);
}

// ---------------- fused BN + ReLU + next linear; fp16 out ----------------
template<int FIN, int FOUT>
__global__ void k_bnlin(const float* __restrict__ acc, const float* __restrict__ dinv,
                        const float* __restrict__ S,
                        const float* __restrict__ g, const float* __restrict__ be,
                        const float* __restrict__ W,
                        __half* __restrict__ hs, int n) {
    __shared__ float sc[FIN], sh[FIN], ws[FIN * FOUT];
    int tid = threadIdx.x;
    if (tid < FIN) {
        float mu = S[tid] / (float)n;
        float var = S[FIN + tid] / (float)n - mu * mu;
        float inv = rsqrtf(var + EPS) * g[tid];
        sc[tid] = inv;
        sh[tid] = be[tid] - mu * inv;
    }
    for (int i = tid; i < FIN * FOUT; i += blockDim.x) ws[i] = W[i];
    __syncthreads();
    int i = blockIdx.x * blockDim.x + tid;
    if (i >= n) return;
    float di = dinv[i];
    float xr[FIN];
    const nf4* ap = (const nf4*)(acc + (size_t)i * FIN);
    #pragma unroll
    for (int q = 0; q < FIN / 4; ++q) {
        nf4 a = __builtin_nontemporal_load(ap + q);
        xr[4*q+0] = fmaxf(fmaf(a.x * di, sc[4*q+0], sh[4*q+0]), 0.f);
        xr[4*q+1] = fmaxf(fmaf(a.y * di, sc[4*q+1], sh[4*q+1]), 0.f);
        xr[4*q+2] = fmaxf(fmaf(a.z * di, sc[4*q+2], sh[4*q+2]), 0.f);
        xr[4*q+3] = fmaxf(fmaf(a.w * di, sc[4*q+3], sh[4*q+3]), 0.f);
    }
    float out[FOUT];
    #pragma unroll
    for (int j = 0; j < FOUT; ++j) {
        float s = 0.f;
        #pragma unroll
        for (int k = 0; k < FIN; ++k) s = fmaf(xr[k], ws[k * FOUT + j], s);
        out[j] = s * di;
    }
    float4 pk[FOUT / 8];
    __half2* ph = (__half2*)pk;
    #pragma unroll
    for (int j = 0; j < FOUT / 2; ++j)
        ph[j] = __floats2half2_rn(out[2*j], out[2*j+1]);
    float4* hp = (float4*)(hs + (size_t)i * FOUT);
    #pragma unroll
    for (int q = 0; q < FOUT / 8; ++q) hp[q] = pk[q];   // cached: gather re-reads these
}

// ---------------- final layer: BN + ReLU + per-block max (no atomics) ------------
__global__ void k_bnmax(const float* __restrict__ acc, const float* __restrict__ dinv,
                        const float* __restrict__ S,
                        const float* __restrict__ g, const float* __restrict__ be,
                        float* __restrict__ bmax, int n) {
    __shared__ float sc[8], sh[8];
    __shared__ float wmax[4 * 8];
    int tid = threadIdx.x;
    if (tid < 8) {
        float mu = S[tid] / (float)n;
        float var = S[8 + tid] / (float)n - mu * mu;
        float inv = rsqrtf(var + EPS) * g[tid];
        sc[tid] = inv;
        sh[tid] = be[tid] - mu * inv;
    }
    __syncthreads();
    int i = blockIdx.x * blockDim.x + tid;
    float vals[8];
    #pragma unroll
    for (int j = 0; j < 8; ++j) vals[j] = 0.f;
    if (i < n) {
        float di = dinv[i];
        const nf4* ap = (const nf4*)(acc + (size_t)i * 8);
        #pragma unroll
        for (int q = 0; q < 2; ++q) {
            nf4 a = __builtin_nontemporal_load(ap + q);
            vals[4*q+0] = fmaxf(fmaf(a.x * di, sc[4*q+0], sh[4*q+0]), 0.f);
            vals[4*q+1] = fmaxf(fmaf(a.y * di, sc[4*q+1], sh[4*q+1]), 0.f);
            vals[4*q+2] = fmaxf(fmaf(a.z * di, sc[4*q+2], sh[4*q+2]), 0.f);
            vals[4*q+3] = fmaxf(fmaf(a.w * di, sc[4*q+3], sh[4*q+3]), 0.f);
        }
    }
    #pragma unroll
    for (int j = 0; j < 8; ++j) {
        #pragma unroll
        for (int off = 32; off > 0; off >>= 1)
            vals[j] = fmaxf(vals[j], __shfl_down(vals[j], off));
    }
    int lane = tid & 63, wid = tid >> 6;
    if (lane == 0) {
        #pragma unroll
        for (int j = 0; j < 8; ++j) wmax[wid * 8 + j] = vals[j];
    }
    __syncthreads();
    if (tid < 8) {
        float m = wmax[tid];
        #pragma unroll
        for (int w = 1; w < 4; ++w) m = fmaxf(m, wmax[w * 8 + tid]);
        bmax[blockIdx.x * 8 + tid] = m;
    }
}

// ---------------- final: reduce per-block maxima, dot with Wout ----------------
__global__ void k_final(const float* __restrict__ bmax, const float* __restrict__ Wout,
                        const float* __restrict__ bout, float* __restrict__ out, int nb) {
    __shared__ float red[64 * 8];
    int tid = threadIdx.x;            // 512 threads: (chunk c, feature j)
    int j = tid & 7, c = tid >> 3;
    float m = 0.f;
    for (int b = c; b < nb; b += 64) m = fmaxf(m, bmax[b * 8 + j]);
    red[c * 8 + j] = m;
    __syncthreads();
    if (tid < 8) {
        float mm = red[tid];
        for (int cc = 1; cc < 64; ++cc) mm = fmaxf(mm, red[cc * 8 + tid]);
        red[tid] = mm;
    }
    __syncthreads();
    if (tid == 0) {
        float s = bout[0];
        #pragma unroll
        for (int k = 0; k < 8; ++k) s = fmaf(red[k], Wout[k], s);
        out[0] = s;
    }
}

extern "C" void kernel_launch(void* const* d_in, const int* in_sizes, int n_in,
                              void* d_out, int out_size, void* d_ws, size_t ws_size,
                              hipStream_t stream) {
    const float* x    = (const float*)d_in[0];
    const int*   ei   = (const int*)d_in[1];
    const float* W1   = (const float*)d_in[2];
    const float* g1   = (const float*)d_in[4];
    const float* be1  = (const float*)d_in[5];
    const float* W2   = (const float*)d_in[6];
    const float* g2   = (const float*)d_in[8];
    const float* be2  = (const float*)d_in[9];
    const float* W3   = (const float*)d_in[10];
    const float* g3   = (const float*)d_in[12];
    const float* be3  = (const float*)d_in[13];
    const float* W4   = (const float*)d_in[14];
    const float* g4   = (const float*)d_in[16];
    const float* be4  = (const float*)d_in[17];
    const float* Wout = (const float*)d_in[18];
    const float* bout = (const float*)d_in[19];
    float* out = (float*)d_out;

    const int N = in_sizes[0] / 128;
    const int E = in_sizes[1] / 2;
    const int* src = ei;
    const int* dst = ei + E;
    const int nbk = (N + 255) >> 8;              // 256-node buckets (391)
    const int gT  = (E + TILE - 1) / TILE;       // bhist blocks (782)
    const int gTp = (E + PTILE - 1) / PTILE;     // partition blocks (391)

    // workspace layout
    char* ws = (char*)d_ws;
    size_t o = 0;
    float* dinv      = (float*)(ws + o); o += 4 * (size_t)N;
    int*   row_start = (int*)(ws + o);   o += 4 * ((size_t)N + 16);
    float* stats     = (float*)(ws + o); o += 4096;
    int*   bhist     = (int*)(ws + o);   o += 2048;
    int*   bcur      = (int*)(ws + o);   o += 2048;
    int*   bstart    = (int*)(ws + o);   o += 4096;
    float* bmax      = (float*)(ws + o); o += 4 * (size_t)(((N + 255) / 256) * 8 + 64);
    size_t hsacc = 96 * (size_t)N;
    if ((size_t)4 * E > hsacc) hsacc = (size_t)4 * E;
    __half* hs       = (__half*)(ws + o);
    float*  acc      = (float*)(ws + o + 32 * (size_t)N);
    unsigned int* part = (unsigned int*)(ws + o);   // dead before k_lin1
    o += hsacc;
    int*   csr_src   = (int*)(ws + o);   o += 4 * (size_t)E;

    const int B = 256;
    int gN  = (N + B - 1) / B;
    int gN4 = (4 * N + B - 1) / B;
    int gN8 = (8 * N + B - 1) / B;

    // ---- graph prep: bucket hist -> scan -> partition -> per-bucket fill ----
    k_init<<<1, 512, 0, stream>>>(stats, bhist);
    k_bhist<<<gT, B, 0, stream>>>(dst, bhist, E, nbk);
    k_bscan<<<1, 512, 0, stream>>>(bhist, bcur, bstart, nbk, E);
    k_part<<<gTp, 512, 0, stream>>>(src, dst, bcur, part, E, nbk);
    k_fill2<<<nbk, 512, 0, stream>>>(part, bstart, dinv, row_start, csr_src, N);

    // ---- layer 1: 128 -> 8 ----
    k_lin1<<<(N + TN - 1) / TN, B, 0, stream>>>(x, W1, dinv, hs, N);
    k_gather<8><<<gN4, B, 0, stream>>>(row_start, csr_src, (const float4*)hs, dinv, acc, stats + 0, N);

    // ---- layer 2: 8 -> 16 ----
    k_bnlin<8, 16><<<gN, B, 0, stream>>>(acc, dinv, stats + 0, g1, be1, W2, hs, N);
    k_gather<16><<<gN8, B, 0, stream>>>(row_start, csr_src, (const float4*)hs, dinv, acc, stats + 32, N);

    // ---- layer 3: 16 -> 16 ----
    k_bnlin<16, 16><<<gN, B, 0, stream>>>(acc, dinv, stats + 32, g2, be2, W3, hs, N);
    k_gather<16><<<gN8, B, 0, stream>>>(row_start, csr_src, (const float4*)hs, dinv, acc, stats + 64, N);

    // ---- layer 4: 16 -> 8 ----
    k_bnlin<16, 8><<<gN, B, 0, stream>>>(acc, dinv, stats + 64, g3, be3, W4, hs, N);
    k_gather<8><<<gN4, B, 0, stream>>>(row_start, csr_src, (const float4*)hs, dinv, acc, stats + 96, N);

    // ---- BN + ReLU + max-pool + output ----
    k_bnmax<<<gN, B, 0, stream>>>(acc, dinv, stats + 96, g4, be4, bmax, N);
    k_final<<<1, 512, 0, stream>>>(bmax, Wout, bout, out, gN);
}

// Round 12
// 384.435 us; speedup vs baseline: 1.1287x; 1.1287x over previous
//
#include <hip/hip_runtime.h>
#include <hip/hip_fp16.h>
#include <cstddef>

#define EPS 1e-5f
#define TILE 4096    // edges per bhist block (16 per thread, block=256)
#define PTILE 8192   // edges per partition block (16 per thread, block=512)

typedef float nf4 __attribute__((ext_vector_type(4)));   // native vec for nontemporal builtins

// ---------------- init: zero stats + bucket histogram ----------------
__global__ void k_init(float* __restrict__ stats, int* __restrict__ bhist) {
    int t = threadIdx.x;            // single block of 512
    if (t < 256) stats[t] = 0.f;    // 4 layers x (S1+S2) blocks of 32 floats
    bhist[t] = 0;                   // 512 >= nbk
}

// ---------------- coarse bucket histogram (dst >> 8), LDS-aggregated ----------------
__global__ void k_bhist(const int* __restrict__ dst, int* __restrict__ bhist,
                        int E, int nbk) {
    __shared__ int hist[512];
    int tid = threadIdx.x;
    int tile0 = blockIdx.x * TILE;
    for (int i = tid; i < nbk; i += 256) hist[i] = 0;
    __syncthreads();
    #pragma unroll
    for (int k = 0; k < 16; ++k) {
        int e = tile0 + k * 256 + tid;
        if (e < E) atomicAdd(&hist[dst[e] >> 8], 1);
    }
    __syncthreads();
    for (int i = tid; i < nbk; i += 256) {
        int c = hist[i];
        if (c) atomicAdd(&bhist[i], c);
    }
}

// ---------------- scan bucket counts -> bucket offsets (1 block of 512) ----------------
__global__ void k_bscan(const int* __restrict__ bhist, int* __restrict__ bcur,
                        int* __restrict__ bstart, int nbk, int E) {
    __shared__ int tmp[512];
    int t = threadIdx.x;
    int v = (t < nbk) ? bhist[t] : 0;
    tmp[t] = v;
    __syncthreads();
    for (int off = 1; off < 512; off <<= 1) {
        int y = (t >= off) ? tmp[t - off] : 0;
        __syncthreads();
        tmp[t] += y;
        __syncthreads();
    }
    if (t < nbk) { int ex = tmp[t] - v; bcur[t] = ex; bstart[t] = ex; }
    if (t == 0) bstart[nbk] = E;
}

// ---------------- partition: edges -> buckets, packed (dlocal<<24)|src ----------------
__global__ void k_part(const int* __restrict__ src, const int* __restrict__ dst,
                       int* __restrict__ bcur, unsigned int* __restrict__ part,
                       int E, int nbk) {
    __shared__ int hist[512];
    __shared__ int base[512];
    int tid = threadIdx.x;
    int tile0 = blockIdx.x * PTILE;
    for (int i = tid; i < nbk; i += 512) hist[i] = 0;
    __syncthreads();
    unsigned int rec[16];
    int bk[16];
    #pragma unroll
    for (int k = 0; k < 16; ++k) {
        int e = tile0 + k * 512 + tid;
        bk[k] = -1;
        if (e < E) {
            int d = dst[e], s = src[e];
            bk[k] = d >> 8;
            rec[k] = ((unsigned int)(d & 255) << 24) | (unsigned int)s;
            atomicAdd(&hist[bk[k]], 1);
        }
    }
    __syncthreads();
    for (int i = tid; i < nbk; i += 512) {
        int c = hist[i];
        base[i] = c ? atomicAdd(&bcur[i], c) : 0;
        hist[i] = 0;
    }
    __syncthreads();
    #pragma unroll
    for (int k = 0; k < 16; ++k) {
        if (bk[k] >= 0) {
            int r = atomicAdd(&hist[bk[k]], 1);
            part[base[bk[k]] + r] = rec[k];
        }
    }
}

// ---------------- per-bucket: degrees -> row_start + dinv, then csr fill ----------
__global__ void k_fill2(const unsigned int* __restrict__ part, const int* __restrict__ bstart,
                        float* __restrict__ dinv, int* __restrict__ row_start,
                        int* __restrict__ csr_src, int N) {
    __shared__ int hist[256];
    __shared__ int cur[256];
    __shared__ int wsum[8];
    int b = blockIdx.x, tid = threadIdx.x;
    int nbase = b << 8;
    int span0 = bstart[b], span1 = bstart[b + 1];
    if (tid < 256) hist[tid] = 0;
    __syncthreads();
    for (int i = span0 + tid; i < span1; i += 512)
        atomicAdd(&hist[part[i] >> 24], 1);
    __syncthreads();
    int v = (tid < 256) ? hist[tid] : 0;
    int lane = tid & 63, wid = tid >> 6;
    int x = v;
    #pragma unroll
    for (int off = 1; off < 64; off <<= 1) {
        int y = __shfl_up(x, off);
        if (lane >= off) x += y;
    }
    if (lane == 63) wsum[wid] = x;
    __syncthreads();
    int add = 0;
    for (int w = 0; w < wid && w < 4; ++w) add += wsum[w];
    int incl = x + add;
    int rs = span0 + incl - v;          // global exclusive offset (valid for tid<256)
    int node = nbase + tid;
    if (tid < 256 && node < N) {
        row_start[node] = rs;
        dinv[node] = rsqrtf((float)(v + 1));   // +1 self loop
        if (node == N - 1) row_start[N] = rs + v;
    }
    if (tid < 256) cur[tid] = rs;
    __syncthreads();
    for (int i = span0 + tid; i < span1; i += 512) {
        unsigned int rec = part[i];
        int p = atomicAdd(&cur[rec >> 24], 1);
        csr_src[p] = (int)(rec & 0xFFFFFFu);
    }
}

// ---------------- layer 1 linear: 128 -> 8, LDS-tiled; fp16 out ----------------
#define TN 64
__global__ void k_lin1(const float* __restrict__ x, const float* __restrict__ W,
                       const float* __restrict__ dinv,
                       __half* __restrict__ hs, int n) {
    __shared__ float xs[TN * 132];
    __shared__ float ws[128 * 8];
    int tid = threadIdx.x;
    int base = blockIdx.x * TN;
    for (int i = tid; i < 1024; i += 256) ws[i] = W[i];
    int nvalid = n - base; if (nvalid > TN) nvalid = TN;
    int limit4 = nvalid * 32;
    const float4* x4 = (const float4*)(x + (size_t)base * 128);
    float4* xs4 = (float4*)xs;
    for (int i = tid; i < TN * 32; i += 256) {
        if (i < limit4) {
            int row = i >> 5, col = i & 31;
            xs4[row * 33 + col] = x4[i];
        }
    }
    __syncthreads();
    #pragma unroll
    for (int rep = 0; rep < 2; ++rep) {
        int o = rep * 256 + tid;
        int node = o >> 3, feat = o & 7;
        if (node < nvalid) {
            const float* xr = xs + node * 132;
            float s = 0.f;
            #pragma unroll 8
            for (int k = 0; k < 128; ++k) s = fmaf(xr[k], ws[k * 8 + feat], s);
            s *= dinv[base + node];
            hs[(size_t)(base + node) * 8 + feat] = __float2half(s);
        }
    }
}

// ---------------- CSR gather (fp16 rows, fp32 accum) + fused BN-stats ------------
// F/4 threads per node: P = F/8 feature-parts x 2 CONTIGUOUS edge-halves.
// 8-deep batch engages when half >= 8 (deg >= 16): ~97% of Poisson(32) rows.
template<int F>
__global__ void k_gather(const int* __restrict__ row_start, const int* __restrict__ csr_src,
                         const float4* __restrict__ hp, const float* __restrict__ dinv,
                         float* __restrict__ acc, float* __restrict__ S, int n) {
    constexpr int P = F / 8;                 // 16B feature chunks per row
    constexpr int LOGP = (P == 2) ? 1 : 0;
    __shared__ float ls[2 * F];
    if (threadIdx.x < 2 * F) ls[threadIdx.x] = 0.f;
    __syncthreads();

    int t = blockIdx.x * blockDim.x + threadIdx.x;
    int node = t >> (LOGP + 1);
    int part = t & (P - 1);
    int sub  = (t >> LOGP) & 1;              // edge-half

    float af[8];
    #pragma unroll
    for (int j = 0; j < 8; ++j) af[j] = 0.f;
    float di = 0.f;

    if (node < n) {
        if (sub == 0) {                      // self-loop term once
            float4 r = hp[(size_t)node * P + part];
            const __half2* h = (const __half2*)&r;
            #pragma unroll
            for (int q = 0; q < 4; ++q) {
                float2 f = __half22float2(h[q]);
                af[2*q] += f.x; af[2*q+1] += f.y;
            }
        }
        int b0 = row_start[node], end0 = row_start[node + 1];
        int half = (end0 - b0 + 1) >> 1;
        int e   = sub ? (b0 + half) : b0;
        int end = sub ? end0 : (b0 + half);
        // 8-deep batch over consecutive edges: 8 independent row loads in flight
        for (; e + 7 < end; e += 8) {
            int sx[8];
            float4 rr[8];
            #pragma unroll
            for (int u = 0; u < 8; ++u) sx[u] = csr_src[e + u];
            #pragma unroll
            for (int u = 0; u < 8; ++u) rr[u] = hp[(size_t)sx[u] * P + part];
            #pragma unroll
            for (int u = 0; u < 8; ++u) {
                const __half2* h = (const __half2*)&rr[u];
                #pragma unroll
                for (int q = 0; q < 4; ++q) {
                    float2 f = __half22float2(h[q]);
                    af[2*q] += f.x; af[2*q+1] += f.y;
                }
            }
        }
        for (; e + 1 < end; e += 2) {
            int s0 = csr_src[e];
            int s1 = csr_src[e + 1];
            float4 r0 = hp[(size_t)s0 * P + part];
            float4 r1 = hp[(size_t)s1 * P + part];
            const __half2* h0 = (const __half2*)&r0;
            const __half2* h1 = (const __half2*)&r1;
            #pragma unroll
            for (int q = 0; q < 4; ++q) {
                float2 f0 = __half22float2(h0[q]);
                float2 f1 = __half22float2(h1[q]);
                af[2*q]   += f0.x + f1.x;
                af[2*q+1] += f0.y + f1.y;
            }
        }
        if (e < end) {
            int s0 = csr_src[e];
            float4 r0 = hp[(size_t)s0 * P + part];
            const __half2* h0 = (const __half2*)&r0;
            #pragma unroll
            for (int q = 0; q < 4; ++q) {
                float2 f0 = __half22float2(h0[q]);
                af[2*q] += f0.x; af[2*q+1] += f0.y;
            }
        }
        // combine the two edge-halves (lanes t and t^P)
        #pragma unroll
        for (int j = 0; j < 8; ++j) af[j] += __shfl_xor(af[j], P);
        if (sub == 0) {
            nf4* ap = (nf4*)(acc + (size_t)node * F + part * 8);
            nf4 o0, o1;
            o0.x = af[0]; o0.y = af[1]; o0.z = af[2]; o0.w = af[3];
            o1.x = af[4]; o1.y = af[5]; o1.z = af[6]; o1.w = af[7];
            __builtin_nontemporal_store(o0, ap);
            __builtin_nontemporal_store(o1, ap + 1);
            di = dinv[node];                 // stays 0 for sub==1 -> stats not double-counted
        }
    }

    float s1v[8], s2v[8];
    #pragma unroll
    for (int j = 0; j < 8; ++j) {
        float v = af[j] * di;
        s1v[j] = v; s2v[j] = v * v;
    }
    #pragma unroll
    for (int j = 0; j < 8; ++j) {
        #pragma unroll
        for (int off = 2 * P; off < 64; off <<= 1) {
            s1v[j] += __shfl_down(s1v[j], off);
            s2v[j] += __shfl_down(s2v[j], off);
        }
    }
    int lane = threadIdx.x & 63;
    if (lane < P) {                          // lanes 0..P-1 are sub==0 feature-parts
        int j0 = part * 8;
        #pragma unroll
        for (int j = 0; j < 8; ++j) {
            atomicAdd(&ls[j0 + j], s1v[j]);
            atomicAdd(&ls[F + j0 + j], s2v[j]);
        }
    }
    __syncthreads();
    if (threadIdx.x < 2 * F) atomicAdd(&S[threadIdx.x], ls[threadIdx.x]);
}

// ---------------- fused BN + ReLU + next linear; fp16 out ----------------
template<int FIN, int FOUT>
__global__ void k_bnlin(const float* __restrict__ acc, const float* __restrict__ dinv,
                        const float* __restrict__ S,
                        const float* __restrict__ g, const float* __restrict__ be,
                        const float* __restrict__ W,
                        __half* __restrict__ hs, int n) {
    __shared__ float sc[FIN], sh[FIN], ws[FIN * FOUT];
    int tid = threadIdx.x;
    if (tid < FIN) {
        float mu = S[tid] / (float)n;
        float var = S[FIN + tid] / (float)n - mu * mu;
        float inv = rsqrtf(var + EPS) * g[tid];
        sc[tid] = inv;
        sh[tid] = be[tid] - mu * inv;
    }
    for (int i = tid; i < FIN * FOUT; i += blockDim.x) ws[i] = W[i];
    __syncthreads();
    int i = blockIdx.x * blockDim.x + tid;
    if (i >= n) return;
    float di = dinv[i];
    float xr[FIN];
    const nf4* ap = (const nf4*)(acc + (size_t)i * FIN);
    #pragma unroll
    for (int q = 0; q < FIN / 4; ++q) {
        nf4 a = __builtin_nontemporal_load(ap + q);
        xr[4*q+0] = fmaxf(fmaf(a.x * di, sc[4*q+0], sh[4*q+0]), 0.f);
        xr[4*q+1] = fmaxf(fmaf(a.y * di, sc[4*q+1], sh[4*q+1]), 0.f);
        xr[4*q+2] = fmaxf(fmaf(a.z * di, sc[4*q+2], sh[4*q+2]), 0.f);
        xr[4*q+3] = fmaxf(fmaf(a.w * di, sc[4*q+3], sh[4*q+3]), 0.f);
    }
    float out[FOUT];
    #pragma unroll
    for (int j = 0; j < FOUT; ++j) {
        float s = 0.f;
        #pragma unroll
        for (int k = 0; k < FIN; ++k) s = fmaf(xr[k], ws[k * FOUT + j], s);
        out[j] = s * di;
    }
    float4 pk[FOUT / 8];
    __half2* ph = (__half2*)pk;
    #pragma unroll
    for (int j = 0; j < FOUT / 2; ++j)
        ph[j] = __floats2half2_rn(out[2*j], out[2*j+1]);
    float4* hp = (float4*)(hs + (size_t)i * FOUT);
    #pragma unroll
    for (int q = 0; q < FOUT / 8; ++q) hp[q] = pk[q];   // cached: gather re-reads these
}

// ---------------- final layer: BN + ReLU + per-block max (no atomics) ------------
__global__ void k_bnmax(const float* __restrict__ acc, const float* __restrict__ dinv,
                        const float* __restrict__ S,
                        const float* __restrict__ g, const float* __restrict__ be,
                        float* __restrict__ bmax, int n) {
    __shared__ float sc[8], sh[8];
    __shared__ float wmax[4 * 8];
    int tid = threadIdx.x;
    if (tid < 8) {
        float mu = S[tid] / (float)n;
        float var = S[8 + tid] / (float)n - mu * mu;
        float inv = rsqrtf(var + EPS) * g[tid];
        sc[tid] = inv;
        sh[tid] = be[tid] - mu * inv;
    }
    __syncthreads();
    int i = blockIdx.x * blockDim.x + tid;
    float vals[8];
    #pragma unroll
    for (int j = 0; j < 8; ++j) vals[j] = 0.f;
    if (i < n) {
        float di = dinv[i];
        const nf4* ap = (const nf4*)(acc + (size_t)i * 8);
        #pragma unroll
        for (int q = 0; q < 2; ++q) {
            nf4 a = __builtin_nontemporal_load(ap + q);
            vals[4*q+0] = fmaxf(fmaf(a.x * di, sc[4*q+0], sh[4*q+0]), 0.f);
            vals[4*q+1] = fmaxf(fmaf(a.y * di, sc[4*q+1], sh[4*q+1]), 0.f);
            vals[4*q+2] = fmaxf(fmaf(a.z * di, sc[4*q+2], sh[4*q+2]), 0.f);
            vals[4*q+3] = fmaxf(fmaf(a.w * di, sc[4*q+3], sh[4*q+3]), 0.f);
        }
    }
    #pragma unroll
    for (int j = 0; j < 8; ++j) {
        #pragma unroll
        for (int off = 32; off > 0; off >>= 1)
            vals[j] = fmaxf(vals[j], __shfl_down(vals[j], off));
    }
    int lane = tid & 63, wid = tid >> 6;
    if (lane == 0) {
        #pragma unroll
        for (int j = 0; j < 8; ++j) wmax[wid * 8 + j] = vals[j];
    }
    __syncthreads();
    if (tid < 8) {
        float m = wmax[tid];
        #pragma unroll
        for (int w = 1; w < 4; ++w) m = fmaxf(m, wmax[w * 8 + tid]);
        bmax[blockIdx.x * 8 + tid] = m;
    }
}

// ---------------- final: reduce per-block maxima, dot with Wout ----------------
__global__ void k_final(const float* __restrict__ bmax, const float* __restrict__ Wout,
                        const float* __restrict__ bout, float* __restrict__ out, int nb) {
    __shared__ float red[64 * 8];
    int tid = threadIdx.x;            // 512 threads: (chunk c, feature j)
    int j = tid & 7, c = tid >> 3;
    float m = 0.f;
    for (int b = c; b < nb; b += 64) m = fmaxf(m, bmax[b * 8 + j]);
    red[c * 8 + j] = m;
    __syncthreads();
    if (tid < 8) {
        float mm = red[tid];
        for (int cc = 1; cc < 64; ++cc) mm = fmaxf(mm, red[cc * 8 + tid]);
        red[tid] = mm;
    }
    __syncthreads();
    if (tid == 0) {
        float s = bout[0];
        #pragma unroll
        for (int k = 0; k < 8; ++k) s = fmaf(red[k], Wout[k], s);
        out[0] = s;
    }
}

extern "C" void kernel_launch(void* const* d_in, const int* in_sizes, int n_in,
                              void* d_out, int out_size, void* d_ws, size_t ws_size,
                              hipStream_t stream) {
    const float* x    = (const float*)d_in[0];
    const int*   ei   = (const int*)d_in[1];
    const float* W1   = (const float*)d_in[2];
    const float* g1   = (const float*)d_in[4];
    const float* be1  = (const float*)d_in[5];
    const float* W2   = (const float*)d_in[6];
    const float* g2   = (const float*)d_in[8];
    const float* be2  = (const float*)d_in[9];
    const float* W3   = (const float*)d_in[10];
    const float* g3   = (const float*)d_in[12];
    const float* be3  = (const float*)d_in[13];
    const float* W4   = (const float*)d_in[14];
    const float* g4   = (const float*)d_in[16];
    const float* be4  = (const float*)d_in[17];
    const float* Wout = (const float*)d_in[18];
    const float* bout = (const float*)d_in[19];
    float* out = (float*)d_out;

    const int N = in_sizes[0] / 128;
    const int E = in_sizes[1] / 2;
    const int* src = ei;
    const int* dst = ei + E;
    const int nbk = (N + 255) >> 8;              // 256-node buckets (391)
    const int gT  = (E + TILE - 1) / TILE;       // bhist blocks (782)
    const int gTp = (E + PTILE - 1) / PTILE;     // partition blocks (391)

    // workspace layout
    char* ws = (char*)d_ws;
    size_t o = 0;
    float* dinv      = (float*)(ws + o); o += 4 * (size_t)N;
    int*   row_start = (int*)(ws + o);   o += 4 * ((size_t)N + 16);
    float* stats     = (float*)(ws + o); o += 4096;
    int*   bhist     = (int*)(ws + o);   o += 2048;
    int*   bcur      = (int*)(ws + o);   o += 2048;
    int*   bstart    = (int*)(ws + o);   o += 4096;
    float* bmax      = (float*)(ws + o); o += 4 * (size_t)(((N + 255) / 256) * 8 + 64);
    size_t hsacc = 96 * (size_t)N;
    if ((size_t)4 * E > hsacc) hsacc = (size_t)4 * E;
    __half* hs       = (__half*)(ws + o);
    float*  acc      = (float*)(ws + o + 32 * (size_t)N);
    unsigned int* part = (unsigned int*)(ws + o);   // dead before k_lin1
    o += hsacc;
    int*   csr_src   = (int*)(ws + o);   o += 4 * (size_t)E;

    const int B = 256;
    int gN  = (N + B - 1) / B;
    int gN2 = (2 * N + B - 1) / B;
    int gN4 = (4 * N + B - 1) / B;

    // ---- graph prep: bucket hist -> scan -> partition -> per-bucket fill ----
    k_init<<<1, 512, 0, stream>>>(stats, bhist);
    k_bhist<<<gT, B, 0, stream>>>(dst, bhist, E, nbk);
    k_bscan<<<1, 512, 0, stream>>>(bhist, bcur, bstart, nbk, E);
    k_part<<<gTp, 512, 0, stream>>>(src, dst, bcur, part, E, nbk);
    k_fill2<<<nbk, 512, 0, stream>>>(part, bstart, dinv, row_start, csr_src, N);

    // ---- layer 1: 128 -> 8 ----
    k_lin1<<<(N + TN - 1) / TN, B, 0, stream>>>(x, W1, dinv, hs, N);
    k_gather<8><<<gN2, B, 0, stream>>>(row_start, csr_src, (const float4*)hs, dinv, acc, stats + 0, N);

    // ---- layer 2: 8 -> 16 ----
    k_bnlin<8, 16><<<gN, B, 0, stream>>>(acc, dinv, stats + 0, g1, be1, W2, hs, N);
    k_gather<16><<<gN4, B, 0, stream>>>(row_start, csr_src, (const float4*)hs, dinv, acc, stats + 32, N);

    // ---- layer 3: 16 -> 16 ----
    k_bnlin<16, 16><<<gN, B, 0, stream>>>(acc, dinv, stats + 32, g2, be2, W3, hs, N);
    k_gather<16><<<gN4, B, 0, stream>>>(row_start, csr_src, (const float4*)hs, dinv, acc, stats + 64, N);

    // ---- layer 4: 16 -> 8 ----
    k_bnlin<16, 8><<<gN, B, 0, stream>>>(acc, dinv, stats + 64, g3, be3, W4, hs, N);
    k_gather<8><<<gN2, B, 0, stream>>>(row_start, csr_src, (const float4*)hs, dinv, acc, stats + 96, N);

    // ---- BN + ReLU + max-pool + output ----
    k_bnmax<<<gN, B, 0, stream>>>(acc, dinv, stats + 96, g4, be4, bmax, N);
    k_final<<<1, 512, 0, stream>>>(bmax, Wout, bout, out, gN);
}